// Round 11
// baseline (151.836 us; speedup 1.0000x reference)
//
#include <hip/hip_runtime.h>
#include <hip/hip_bf16.h>

// HalfKP input layer, king-grouped MFMA, 32-row chunks + K-split waves:
//   per king k: D = A_k (nc x 672 bf16 0/1) x W_k (672x256 -> bf16 on the fly)
//   out[b,c] = bias[c] + D[entry(b,0)] + D[entry(b,1)]
// B=1024, K=64, F=640(+row 640), C=256. W is (64,641,256) fp32 = 42 MB.
//
// R11 vs R10: with n_k ~ 32, R10's 64-row M-chunk made half the MFMA/A/B work
// compute zeros. (a) M-chunk = 32 rows; waves = (mt x ntc x kh); (b) K halves
// split across wave pairs, ONE pairwise LDS reduce (1 barrier); (c) fully
// unrolled windows (compile-time addresses) + v_cvt_pk_bf16_f32 (gfx950,
// learn_hip m240: asm-only) cut per-window VALU ~3x. List build, mask build,
// A/B/D lane mappings carried over verbatim (HW-verified, absmax 0.5).

#define F_DIM 640
#define C_DIM 256
#define SLAB_STRIDE (641 * 256)   // floats per king slab
#define NKING 64
#define LCAP 256                  // list capacity per king
#define NC_MAX 64                 // max 64-entry chunks (nent <= 4096)

// ws layout (bytes)
#define WS_MASK_OFF 0                        // 1024*10*8 = 80 KB
#define WS_PART_OFF 81920                    // 2*1024*256*4 = 2 MB
#define WS_NEED (WS_PART_OFF + 2 * 1024 * 256 * 4)

typedef float  f32x4  __attribute__((ext_vector_type(4)));
typedef short  bf16x8 __attribute__((ext_vector_type(8)));

__device__ __forceinline__ bf16x8 mk_a8(unsigned m32, int g) {
    // A-frag: 8 bf16 0/1 from byte g of a 32-bit window mask (k = g*8 + j)
    const unsigned by = (m32 >> (g * 8)) & 0xFFu;
    union { unsigned u[4]; bf16x8 v; } r;
    #pragma unroll
    for (int i = 0; i < 4; ++i)
        r.u[i] = (((by >> (2 * i)) & 1u) ? 0x3F80u : 0u) |
                 (((by >> (2 * i + 1)) & 1u) ? 0x3F800000u : 0u);
    return r.v;
}

__device__ __forceinline__ f32x4 do_win(const float* __restrict__ Wc,
                                        unsigned m32, int g, int ks, f32x4 acc) {
    float wt[8];
    #pragma unroll
    for (int j = 0; j < 8; ++j)
        wt[j] = Wc[(size_t)(ks * 32 + g * 8 + j) * C_DIM];
    union { unsigned u[4]; bf16x8 v; } bb;
    #pragma unroll
    for (int j = 0; j < 4; ++j)   // D.lo=cvt(S0), D.hi=cvt(S1): k ascending
        asm("v_cvt_pk_bf16_f32 %0, %1, %2"
            : "=v"(bb.u[j]) : "v"(wt[2 * j]), "v"(wt[2 * j + 1]));
    const bf16x8 af = mk_a8(m32, g);
    return __builtin_amdgcn_mfma_f32_16x16x32_bf16(af, bb.v, acc, 0, 0, 0);
}

__global__ __launch_bounds__(256)
void pack_masks(const int* __restrict__ pieces,          // (B,640) int32 0/1
                unsigned long long* __restrict__ mask,   // (B,10)
                int nwords)                              // B*10
{
    const int gw = blockIdx.x * 4 + (threadIdx.x >> 6);
    const int lane = threadIdx.x & 63;
    if (gw >= nwords) return;
    const int v = pieces[(size_t)gw * 64 + lane];
    const unsigned long long m = __ballot(v != 0);
    if (lane == 0) mask[gw] = m;
}

__global__ __launch_bounds__(512, 4)
void halfkp_mfma(const float* __restrict__ W,                 // (64,641,256)
                 const unsigned long long* __restrict__ mask, // (B,10)
                 const int* __restrict__ kings,               // flat (B*2)
                 float* __restrict__ partial,                 // (2,B,256)
                 int nent)
{
    const int k  = blockIdx.x;
    const int cq = blockIdx.y;               // 0..7, 32 cols each
    const int t  = threadIdx.x;
    const int wv = t >> 6, lane = t & 63;
    const int mt  = wv & 1;                  // M-tile 0..1 (rows mt*16+..)
    const int ntc = (wv >> 1) & 1;           // N-half 0..1
    const int kh  = wv >> 2;                 // K-half 0..1
    const int li = lane & 15, g = lane >> 4;
    const int col = cq * 32 + ntc * 16 + li;

    __shared__ int s_ent[LCAP];
    __shared__ int s_cb[NC_MAX + 1];
    __shared__ unsigned s_m32[32][21];       // per-row window masks (2.7 KB)
    __shared__ f32x4 s_red[4][64];           // 4 KB pairwise K-reduce
    __shared__ int s_nk;

    // ---- in-block list build (R10-verified): stable compaction ----
    const int NC = nent >> 6;                // 64-entry chunks
    const int nit = NC >> 3;                 // chunks per wave (8 waves)
    unsigned long long mm[8];
    #pragma unroll
    for (int it = 0; it < 8; ++it) {
        if (it < nit) {
            const int c = wv + (it << 3);
            const int kk = kings[(c << 6) + lane];   // flat index == entry id
            mm[it] = __ballot(kk == k);
            if (lane == 0) s_cb[c] = (int)__popcll(mm[it]);
        }
    }
    __syncthreads();
    if (t == 0) {
        int s = 0;
        for (int c = 0; c < NC; ++c) { const int v = s_cb[c]; s_cb[c] = s; s += v; }
        s_nk = min(s, LCAP);
    }
    __syncthreads();
    const unsigned long long lt = (1ull << lane) - 1ull;
    #pragma unroll
    for (int it = 0; it < 8; ++it) {
        if (it < nit) {
            const int c = wv + (it << 3);
            if ((mm[it] >> lane) & 1ull) {
                const int pos = s_cb[c] + (int)__popcll(mm[it] & lt);
                if (pos < LCAP) s_ent[pos] = (c << 6) + lane;
            }
        }
    }
    __syncthreads();
    const int n_k = s_nk;

    const float* __restrict__ Wc = W + (size_t)k * SLAB_STRIDE + col;

    for (int mb = 0; mb < n_k; mb += 32) {
        const int nc = min(n_k - mb, 32);

        // window ks covers features [ks*32, ks*32+32); ks=20: only row 640.
        for (int idx = t; idx < 32 * 21; idx += 512) {
            const int row = idx & 31, ks = idx >> 5;
            const int id = (row < nc) ? s_ent[mb + row] : -1;
            unsigned v = 0;
            if (id >= 0) {
                if (ks < 20) {
                    const unsigned long long mw = mask[(size_t)(id >> 1) * 10 + (ks >> 1)];
                    v = (unsigned)(mw >> ((ks & 1) * 32));
                } else {
                    v = 1u;                  // always-active row 640
                }
            }
            s_m32[row][ks] = v;
        }
        __syncthreads();

        // ---- wave-private MFMA over this wave's K-half ----
        const unsigned* mrow = s_m32[mt * 16 + li];
        f32x4 acc = {0.f, 0.f, 0.f, 0.f};
        if (kh == 0) {
            #pragma unroll
            for (int ks = 0; ks < 10; ++ks)
                acc = do_win(Wc, mrow[ks], g, ks, acc);
        } else {
            #pragma unroll
            for (int ks = 10; ks < 20; ++ks)
                acc = do_win(Wc, mrow[ks], g, ks, acc);
            {   // window 20: only feature 640 (k-slot 0) is live
                const float w640 = Wc[(size_t)F_DIM * C_DIM];
                unsigned pk;
                asm("v_cvt_pk_bf16_f32 %0, %1, %2" : "=v"(pk) : "v"(w640), "v"(w640));
                union { unsigned u[4]; bf16x8 v; } bb;
                bb.u[0] = bb.u[1] = bb.u[2] = bb.u[3] = pk;
                const bf16x8 af = mk_a8(mrow[20], g);
                acc = __builtin_amdgcn_mfma_f32_16x16x32_bf16(af, bb.v, acc, 0, 0, 0);
            }
            s_red[wv & 3][lane] = acc;       // publish K-half 1
        }
        __syncthreads();
        if (kh == 0) {
            acc += s_red[wv & 3][lane];      // same (mt,ntc) partner wave
            // D: reg i -> row = mt*16 + 4*g + i, col = col (m89-verified)
            #pragma unroll
            for (int i = 0; i < 4; ++i) {
                const int row = mt * 16 + 4 * g + i;
                if (row < nc) {
                    const int id = s_ent[mb + row];
                    partial[(((size_t)(id & 1)) * 1024 + (id >> 1)) * C_DIM + col] = acc[i];
                }
            }
        }
        __syncthreads();   // protect s_m32/s_red before next chunk
    }
}

__global__ __launch_bounds__(256)
void finalize(const float* __restrict__ partial,
              const float* __restrict__ bias,
              float* __restrict__ out)
{
    const int i = blockIdx.x * 256 + threadIdx.x;    // float4 index, B*64 total
    const float4 b4 = ((const float4*)bias)[i & 63];
    const float4 p0 = ((const float4*)partial)[i];
    const float4 p1 = ((const float4*)partial)[1024 * 64 + i];
    float4 o;
    o.x = b4.x + p0.x + p1.x;
    o.y = b4.y + p0.y + p1.y;
    o.z = b4.z + p0.z + p1.z;
    o.w = b4.w + p0.w + p1.w;
    ((float4*)out)[i] = o;
}

// ---- fallback (R3 path) if ws is too small ----
__global__ __launch_bounds__(256)
void halfkp_fallback(const int* __restrict__ pieces, const int* __restrict__ kings,
                     const float* __restrict__ W, const float* __restrict__ bias,
                     float* __restrict__ out)
{
    const int b = blockIdx.x;
    const int c = threadIdx.x;
    const int lane = c & 63;
    const int k0 = kings[2 * b + 0];
    const int k1 = kings[2 * b + 1];
    const float* W0 = W + (size_t)k0 * SLAB_STRIDE + c;
    const float* W1 = W + (size_t)k1 * SLAB_STRIDE + c;
    float acc = bias[c] + W0[640 * 256] + W1[640 * 256];
    const int* pi = pieces + (size_t)b * F_DIM;
    #pragma unroll
    for (int ch = 0; ch < 10; ++ch) {
        int v = pi[ch * 64 + lane];
        unsigned long long m = __ballot(v != 0);
        const float* b0 = W0 + ch * 64 * 256;
        const float* b1 = W1 + ch * 64 * 256;
        while (m) {
            const int f = __builtin_ctzll(m);
            m &= m - 1;
            acc += b0[f * 256] + b1[f * 256];
        }
    }
    out[(size_t)b * C_DIM + c] = acc;
}

extern "C" void kernel_launch(void* const* d_in, const int* in_sizes, int n_in,
                              void* d_out, int out_size, void* d_ws, size_t ws_size,
                              hipStream_t stream) {
    const int* pieces = (const int*)d_in[0];   // (1024, 640) int32 bools
    const int* kings  = (const int*)d_in[1];   // (1024, 2) int32
    const float* W    = (const float*)d_in[2]; // (64, 641, 256) f32
    const float* bias = (const float*)d_in[3]; // (256,) f32
    float* out        = (float*)d_out;         // (1024, 256) f32

    const int B = in_sizes[1] / 2;             // 1024
    const int nent = 2 * B;
    const int nwords = B * 10;

    if (ws_size < (size_t)WS_NEED) {
        halfkp_fallback<<<dim3(B), dim3(C_DIM), 0, stream>>>(pieces, kings, W, bias, out);
        return;
    }

    unsigned long long* mask = (unsigned long long*)((char*)d_ws + WS_MASK_OFF);
    float* part = (float*)((char*)d_ws + WS_PART_OFF);

    pack_masks<<<dim3((nwords + 3) / 4), dim3(256), 0, stream>>>(pieces, mask, nwords);
    halfkp_mfma<<<dim3(NKING, 8), dim3(512), 0, stream>>>(W, mask, kings, part, nent);
    finalize<<<dim3(B * 64 / 256), dim3(256), 0, stream>>>(part, bias, out);
}

// Round 12
// 27.998 us; speedup vs baseline: 5.4230x; 5.4230x over previous
//
#include <hip/hip_runtime.h>
#include <hip/hip_bf16.h>

// HalfKP input layer, king-grouped MFMA, 32-row chunks + K-split waves:
//   per king k: D = A_k (nc x 672 bf16 0/1) x W_k (672x256 -> bf16 on the fly)
//   out[b,c] = bias[c] + D[entry(b,0)] + D[entry(b,1)]
// B=1024, K=64, F=640(+row 640), C=256. W is (64,641,256) fp32 = 42 MB.
//
// R12 vs R11: R11's full `#pragma unroll` over 10 windows exploded register
// liveness (compiler hoisted ~80 loads) -> spill storm (WRITE_SIZE 225 MB of
// scratch, 160us). Fix: `#pragma unroll 2` bounds in-flight state to ~35
// VGPRs (16 loads in flight = enough ILP); mm[] scoped so its liveness ends
// at the hot loop. Everything else identical to R11 (verified absmax 0.5).

#define F_DIM 640
#define C_DIM 256
#define SLAB_STRIDE (641 * 256)   // floats per king slab
#define NKING 64
#define LCAP 256                  // list capacity per king
#define NC_MAX 64                 // max 64-entry chunks (nent <= 4096)

// ws layout (bytes)
#define WS_MASK_OFF 0                        // 1024*10*8 = 80 KB
#define WS_PART_OFF 81920                    // 2*1024*256*4 = 2 MB
#define WS_NEED (WS_PART_OFF + 2 * 1024 * 256 * 4)

typedef float  f32x4  __attribute__((ext_vector_type(4)));
typedef short  bf16x8 __attribute__((ext_vector_type(8)));

__device__ __forceinline__ bf16x8 mk_a8(unsigned m32, int g) {
    // A-frag: 8 bf16 0/1 from byte g of a 32-bit window mask (k = g*8 + j)
    const unsigned by = (m32 >> (g * 8)) & 0xFFu;
    union { unsigned u[4]; bf16x8 v; } r;
    #pragma unroll
    for (int i = 0; i < 4; ++i)
        r.u[i] = (((by >> (2 * i)) & 1u) ? 0x3F80u : 0u) |
                 (((by >> (2 * i + 1)) & 1u) ? 0x3F800000u : 0u);
    return r.v;
}

__device__ __forceinline__ f32x4 do_win(const float* __restrict__ Wc,
                                        unsigned m32, int g, int ks, f32x4 acc) {
    float wt[8];
    #pragma unroll
    for (int j = 0; j < 8; ++j)
        wt[j] = Wc[(size_t)(ks * 32 + g * 8 + j) * C_DIM];
    union { unsigned u[4]; bf16x8 v; } bb;
    #pragma unroll
    for (int j = 0; j < 4; ++j)   // D.lo=cvt(S0), D.hi=cvt(S1): k ascending
        asm("v_cvt_pk_bf16_f32 %0, %1, %2"
            : "=v"(bb.u[j]) : "v"(wt[2 * j]), "v"(wt[2 * j + 1]));
    const bf16x8 af = mk_a8(m32, g);
    return __builtin_amdgcn_mfma_f32_16x16x32_bf16(af, bb.v, acc, 0, 0, 0);
}

__global__ __launch_bounds__(256)
void pack_masks(const int* __restrict__ pieces,          // (B,640) int32 0/1
                unsigned long long* __restrict__ mask,   // (B,10)
                int nwords)                              // B*10
{
    const int gw = blockIdx.x * 4 + (threadIdx.x >> 6);
    const int lane = threadIdx.x & 63;
    if (gw >= nwords) return;
    const int v = pieces[(size_t)gw * 64 + lane];
    const unsigned long long m = __ballot(v != 0);
    if (lane == 0) mask[gw] = m;
}

__global__ __launch_bounds__(512, 4)
void halfkp_mfma(const float* __restrict__ W,                 // (64,641,256)
                 const unsigned long long* __restrict__ mask, // (B,10)
                 const int* __restrict__ kings,               // flat (B*2)
                 float* __restrict__ partial,                 // (2,B,256)
                 int nent)
{
    const int k  = blockIdx.x;
    const int cq = blockIdx.y;               // 0..7, 32 cols each
    const int t  = threadIdx.x;
    const int wv = t >> 6, lane = t & 63;
    const int mt  = wv & 1;                  // M-tile 0..1 (rows mt*16+..)
    const int ntc = (wv >> 1) & 1;           // N-half 0..1
    const int kh  = wv >> 2;                 // K-half 0..1
    const int li = lane & 15, g = lane >> 4;
    const int col = cq * 32 + ntc * 16 + li;

    __shared__ int s_ent[LCAP];
    __shared__ int s_cb[NC_MAX + 1];
    __shared__ unsigned s_m32[32][21];       // per-row window masks (2.7 KB)
    __shared__ f32x4 s_red[4][64];           // 4 KB pairwise K-reduce
    __shared__ int s_nk;

    // ---- in-block list build (R10-verified): stable compaction ----
    {
        const int NC = nent >> 6;            // 64-entry chunks
        const int nit = NC >> 3;             // chunks per wave (8 waves)
        unsigned long long mm[8];
        #pragma unroll
        for (int it = 0; it < 8; ++it) {
            if (it < nit) {
                const int c = wv + (it << 3);
                const int kk = kings[(c << 6) + lane];   // flat idx == entry id
                mm[it] = __ballot(kk == k);
                if (lane == 0) s_cb[c] = (int)__popcll(mm[it]);
            }
        }
        __syncthreads();
        if (t == 0) {
            int s = 0;
            for (int c = 0; c < NC; ++c) { const int v = s_cb[c]; s_cb[c] = s; s += v; }
            s_nk = min(s, LCAP);
        }
        __syncthreads();
        const unsigned long long lt = (1ull << lane) - 1ull;
        #pragma unroll
        for (int it = 0; it < 8; ++it) {
            if (it < nit) {
                const int c = wv + (it << 3);
                if ((mm[it] >> lane) & 1ull) {
                    const int pos = s_cb[c] + (int)__popcll(mm[it] & lt);
                    if (pos < LCAP) s_ent[pos] = (c << 6) + lane;
                }
            }
        }
        __syncthreads();
    }
    const int n_k = s_nk;

    const float* __restrict__ Wc = W + (size_t)k * SLAB_STRIDE + col;

    for (int mb = 0; mb < n_k; mb += 32) {
        const int nc = min(n_k - mb, 32);

        // window ks covers features [ks*32, ks*32+32); ks=20: only row 640.
        for (int idx = t; idx < 32 * 21; idx += 512) {
            const int row = idx & 31, ks = idx >> 5;
            const int id = (row < nc) ? s_ent[mb + row] : -1;
            unsigned v = 0;
            if (id >= 0) {
                if (ks < 20) {
                    const unsigned long long mw = mask[(size_t)(id >> 1) * 10 + (ks >> 1)];
                    v = (unsigned)(mw >> ((ks & 1) * 32));
                } else {
                    v = 1u;                  // always-active row 640
                }
            }
            s_m32[row][ks] = v;
        }
        __syncthreads();

        // ---- wave-private MFMA over this wave's K-half (unroll BOUNDED) ----
        const unsigned* mrow = s_m32[mt * 16 + li];
        f32x4 acc = {0.f, 0.f, 0.f, 0.f};
        if (kh == 0) {
            #pragma unroll 2
            for (int ks = 0; ks < 10; ++ks)
                acc = do_win(Wc, mrow[ks], g, ks, acc);
        } else {
            #pragma unroll 2
            for (int ks = 10; ks < 20; ++ks)
                acc = do_win(Wc, mrow[ks], g, ks, acc);
            {   // window 20: only feature 640 (k-slot 0) is live
                const float w640 = Wc[(size_t)F_DIM * C_DIM];
                unsigned pk;
                asm("v_cvt_pk_bf16_f32 %0, %1, %2" : "=v"(pk) : "v"(w640), "v"(w640));
                union { unsigned u[4]; bf16x8 v; } bb;
                bb.u[0] = bb.u[1] = bb.u[2] = bb.u[3] = pk;
                const bf16x8 af = mk_a8(mrow[20], g);
                acc = __builtin_amdgcn_mfma_f32_16x16x32_bf16(af, bb.v, acc, 0, 0, 0);
            }
            s_red[wv & 3][lane] = acc;       // publish K-half 1
        }
        __syncthreads();
        if (kh == 0) {
            acc += s_red[wv & 3][lane];      // same (mt,ntc) partner wave
            // D: reg i -> row = mt*16 + 4*g + i, col = col (m89-verified)
            #pragma unroll
            for (int i = 0; i < 4; ++i) {
                const int row = mt * 16 + 4 * g + i;
                if (row < nc) {
                    const int id = s_ent[mb + row];
                    partial[(((size_t)(id & 1)) * 1024 + (id >> 1)) * C_DIM + col] = acc[i];
                }
            }
        }
        __syncthreads();   // protect s_m32/s_red before next chunk
    }
}

__global__ __launch_bounds__(256)
void finalize(const float* __restrict__ partial,
              const float* __restrict__ bias,
              float* __restrict__ out)
{
    const int i = blockIdx.x * 256 + threadIdx.x;    // float4 index, B*64 total
    const float4 b4 = ((const float4*)bias)[i & 63];
    const float4 p0 = ((const float4*)partial)[i];
    const float4 p1 = ((const float4*)partial)[1024 * 64 + i];
    float4 o;
    o.x = b4.x + p0.x + p1.x;
    o.y = b4.y + p0.y + p1.y;
    o.z = b4.z + p0.z + p1.z;
    o.w = b4.w + p0.w + p1.w;
    ((float4*)out)[i] = o;
}

// ---- fallback (R3 path) if ws is too small ----
__global__ __launch_bounds__(256)
void halfkp_fallback(const int* __restrict__ pieces, const int* __restrict__ kings,
                     const float* __restrict__ W, const float* __restrict__ bias,
                     float* __restrict__ out)
{
    const int b = blockIdx.x;
    const int c = threadIdx.x;
    const int lane = c & 63;
    const int k0 = kings[2 * b + 0];
    const int k1 = kings[2 * b + 1];
    const float* W0 = W + (size_t)k0 * SLAB_STRIDE + c;
    const float* W1 = W + (size_t)k1 * SLAB_STRIDE + c;
    float acc = bias[c] + W0[640 * 256] + W1[640 * 256];
    const int* pi = pieces + (size_t)b * F_DIM;
    #pragma unroll
    for (int ch = 0; ch < 10; ++ch) {
        int v = pi[ch * 64 + lane];
        unsigned long long m = __ballot(v != 0);
        const float* b0 = W0 + ch * 64 * 256;
        const float* b1 = W1 + ch * 64 * 256;
        while (m) {
            const int f = __builtin_ctzll(m);
            m &= m - 1;
            acc += b0[f * 256] + b1[f * 256];
        }
    }
    out[(size_t)b * C_DIM + c] = acc;
}

extern "C" void kernel_launch(void* const* d_in, const int* in_sizes, int n_in,
                              void* d_out, int out_size, void* d_ws, size_t ws_size,
                              hipStream_t stream) {
    const int* pieces = (const int*)d_in[0];   // (1024, 640) int32 bools
    const int* kings  = (const int*)d_in[1];   // (1024, 2) int32
    const float* W    = (const float*)d_in[2]; // (64, 641, 256) f32
    const float* bias = (const float*)d_in[3]; // (256,) f32
    float* out        = (float*)d_out;         // (1024, 256) f32

    const int B = in_sizes[1] / 2;             // 1024
    const int nent = 2 * B;
    const int nwords = B * 10;

    if (ws_size < (size_t)WS_NEED) {
        halfkp_fallback<<<dim3(B), dim3(C_DIM), 0, stream>>>(pieces, kings, W, bias, out);
        return;
    }

    unsigned long long* mask = (unsigned long long*)((char*)d_ws + WS_MASK_OFF);
    float* part = (float*)((char*)d_ws + WS_PART_OFF);

    pack_masks<<<dim3((nwords + 3) / 4), dim3(256), 0, stream>>>(pieces, mask, nwords);
    halfkp_mfma<<<dim3(NKING, 8), dim3(512), 0, stream>>>(W, mask, kings, part, nent);
    finalize<<<dim3(B * 64 / 256), dim3(256), 0, stream>>>(part, bias, out);
}